// Round 7
// baseline (627.574 us; speedup 1.0000x reference)
//
#include <hip/hip_runtime.h>
#include <hip/hip_cooperative_groups.h>

namespace cg = cooperative_groups;

// Attention_msa_TwoStream. Only v_cls (d_in[1]) feeds outputs (MLP/q/k dead).
// N=3200, H=8, d=64, C=512; fp32 I/O; bf16 MFMA internals.
// SINGLE cooperative kernel, 3 phases separated by __threadfence()+grid.sync():
//   P: per-(n,h) L2 norm -> vnfull bf16 + vT/vnT transposes + x_ori. (400 u)
//   R: u<16: G_h halves (NT GEMM from vT/vnT);
//      u>=16: R=1/8 vn.vn^T upper-tri 128x128 tiles, BK=32 LDS dbuf with
//      counted vmcnt(4)+s_barrier (r3 form, best measured); epilogue stages
//      both orientations via LDS -> full 256B coalesced rows.     (341 u)
//   F: sm rows (Z/E sum+normalize -> out2) | X tiles (vn.(G0+G1) - corr). (1200 u)
// Fences: each inter-phase buffer is first-touch-after-write, so one
// device-scope release fence (L2 writeback) before each grid.sync suffices.
// Fallback: if cooperative launch fails, same kernel runs as 3 dispatches.

#define NN 3200
#define HEADS 8
#define DH 64
#define CC 512

typedef __attribute__((ext_vector_type(8))) short short8;   // 8 bf16
typedef __attribute__((ext_vector_type(4))) float f32x4;

static __device__ __forceinline__ unsigned short f2b(float f) {
  union { float f; unsigned u; } x; x.f = f;
  unsigned r = x.u + 0x7FFFu + ((x.u >> 16) & 1u);   // RTN-even
  return (unsigned short)(r >> 16);
}
static __device__ __forceinline__ float b2f(unsigned short s) {
  union { unsigned u; float f; } x; x.u = ((unsigned)s) << 16; return x.f;
}
static __device__ __forceinline__ short8 pack8(f32x4 lo, f32x4 hi) {
  short8 r;
  r[0] = (short)f2b(lo[0]); r[1] = (short)f2b(lo[1]);
  r[2] = (short)f2b(lo[2]); r[3] = (short)f2b(lo[3]);
  r[4] = (short)f2b(hi[0]); r[5] = (short)f2b(hi[1]);
  r[6] = (short)f2b(hi[2]); r[7] = (short)f2b(hi[3]);
  return r;
}

typedef const void __attribute__((address_space(1))) gvoid_t;
typedef void __attribute__((address_space(3))) lvoid_t;
static __device__ __forceinline__ void gl_lds16(const void* g, void* l) {
  __builtin_amdgcn_global_load_lds((gvoid_t*)g, (lvoid_t*)l, 16, 0, 0);
}

__global__ __launch_bounds__(256, 4) void k_all(const float* __restrict__ v,
                                                unsigned short* __restrict__ vnfull,
                                                unsigned short* __restrict__ vT,
                                                unsigned short* __restrict__ vnT,
                                                float* __restrict__ Gf,
                                                unsigned short* __restrict__ Rg,
                                                float* __restrict__ out2,
                                                float* __restrict__ out,
                                                int phase) {
  __shared__ __align__(16) unsigned short S[16384];   // 32 KB, reused per phase
  int tid = threadIdx.x;
  int lane = tid & 63, quad = lane >> 4, l16 = lane & 15;
  int nb = (int)gridDim.x;

  // ===================== phase P: prep (units 0..399) ======================
  if (phase & 1) {
    unsigned short* tileV = S;            // [64][72]
    unsigned short* tileN = S + 4608;     // [64][72]
    int j = lane;            // dim within head
    int w = tid >> 6;        // wave = row group
    for (int u = (int)blockIdx.x; u < 400; u += nb) {
      int h  = u & 7;
      int n0 = (u >> 3) * 64;
      #pragma unroll
      for (int i = 0; i < 16; i++) {
        int n = n0 + w * 16 + i;
        float val = v[(size_t)n * CC + h * DH + j];
        float ss = val * val;
        #pragma unroll
        for (int off = 32; off >= 1; off >>= 1) ss += __shfl_xor(ss, off, 64);
        float inv = 1.0f / (sqrtf(ss) + 1e-8f);
        unsigned short un = f2b(val * inv);
        tileV[j * 72 + w * 16 + i] = f2b(val);
        tileN[j * 72 + w * 16 + i] = un;
        vnfull[(size_t)n * CC + h * DH + j] = un;
        __builtin_nontemporal_store(val, out + (size_t)n * (2 * CC) + CC + h * DH + j);
      }
      __syncthreads();
      #pragma unroll
      for (int i = 0; i < 16; i++) {
        int jj = w * 16 + i;
        __builtin_nontemporal_store(tileV[jj * 72 + j], vT  + ((size_t)h * DH + jj) * NN + n0 + j);
        __builtin_nontemporal_store(tileN[jj * 72 + j], vnT + ((size_t)h * DH + jj) * NN + n0 + j);
      }
      __syncthreads();
    }
  }
  if (phase == 7) { __threadfence(); cg::this_grid().sync(); }

  // ===================== phase R: G + R tiles (units 0..340) ===============
  if (phase & 2) {
    for (int u = (int)blockIdx.x; u < 341; u += nb) {
      if (u < 16) {
        // ---- G partial: G[half][h][d][k] = sum_{m in half} V[m][d]*vn[m][k]
        int h = u >> 1, half = u & 1, w = tid >> 6;
        int mbase = half * 1600;
        const unsigned short* aP = vT + (size_t)(h * DH + w * 16 + l16) * NN + quad * 8 + mbase;
        const unsigned short* bP[4];
        #pragma unroll
        for (int ct = 0; ct < 4; ct++)
          bP[ct] = vnT + (size_t)(h * DH + ct * 16 + l16) * NN + quad * 8 + mbase;
        f32x4 acc4[4];
        #pragma unroll
        for (int ct = 0; ct < 4; ct++) acc4[ct] = (f32x4){0.f, 0.f, 0.f, 0.f};
        #pragma unroll 2
        for (int m0 = 0; m0 < 1600; m0 += 64) {
          short8 a0 = *(const short8*)(aP + m0);
          short8 a1 = *(const short8*)(aP + m0 + 32);
          #pragma unroll
          for (int ct = 0; ct < 4; ct++) {
            short8 b0 = *(const short8*)(bP[ct] + m0);
            short8 b1 = *(const short8*)(bP[ct] + m0 + 32);
            acc4[ct] = __builtin_amdgcn_mfma_f32_16x16x32_bf16(a0, b0, acc4[ct], 0, 0, 0);
            acc4[ct] = __builtin_amdgcn_mfma_f32_16x16x32_bf16(a1, b1, acc4[ct], 0, 0, 0);
          }
        }
        #pragma unroll
        for (int ct = 0; ct < 4; ct++)
          #pragma unroll
          for (int g = 0; g < 4; g++)
            Gf[(size_t)half * 32768 + h * 4096 +
               (w * 16 + quad * 4 + g) * 64 + ct * 16 + l16] = acc4[ct][g];
        continue;
      }
      // ---- R tile (r3 form): upper-tri map, LDS dbuf, counted vmcnt ------
      int bid = u - 16, bi = 0;
      while (bid >= 25 - bi) { bid -= 25 - bi; bi++; }
      int bj = bi + bid;
      int n0 = bi * 128, m0 = bj * 128;
      int wv = tid >> 6, wr = wv >> 1, wc = wv & 1;
      #define AsBase(buf) (S + (buf) * 4096)
      #define BsBase(buf) (S + 8192 + (buf) * 4096)

      const unsigned short* aG[2];
      const unsigned short* bG[2];
      int sl[2];
      #pragma unroll
      for (int t = 0; t < 2; t++) {
        int s = tid + t * 256;
        sl[t] = s;
        int row = ((s >> 5) << 3) | (s & 7), kc = (s >> 3) & 3;
        aG[t] = vnfull + (size_t)(n0 + row) * CC + kc * 8;
        bG[t] = vnfull + (size_t)(m0 + row) * CC + kc * 8;
      }
      int roA[4], roB[4];
      #pragma unroll
      for (int rt = 0; rt < 4; rt++) {
        int row = wr * 64 + rt * 16 + l16;
        roA[rt] = (row >> 3) * 256 + (row & 7) * 8;
      }
      #pragma unroll
      for (int ct = 0; ct < 4; ct++) {
        int row = wc * 64 + ct * 16 + l16;
        roB[ct] = (row >> 3) * 256 + (row & 7) * 8;
      }
      f32x4 acc[4][4];
      #pragma unroll
      for (int rt = 0; rt < 4; rt++)
        #pragma unroll
        for (int ct = 0; ct < 4; ct++) acc[rt][ct] = (f32x4){0.f, 0.f, 0.f, 0.f};

      #pragma unroll
      for (int t = 0; t < 2; t++) gl_lds16(aG[t], AsBase(0) + sl[t] * 8);
      #pragma unroll
      for (int t = 0; t < 2; t++) gl_lds16(bG[t], BsBase(0) + sl[t] * 8);

      #pragma unroll 1
      for (int kk = 0; kk < 16; kk++) {
        int buf = kk & 1;
        if (kk < 15) {
          int ko = (kk + 1) * 32;
          #pragma unroll
          for (int t = 0; t < 2; t++) gl_lds16(aG[t] + ko, AsBase(buf ^ 1) + sl[t] * 8);
          #pragma unroll
          for (int t = 0; t < 2; t++) gl_lds16(bG[t] + ko, BsBase(buf ^ 1) + sl[t] * 8);
          asm volatile("s_waitcnt vmcnt(4)" ::: "memory");
        } else {
          asm volatile("s_waitcnt vmcnt(0)" ::: "memory");
        }
        __builtin_amdgcn_s_barrier();
        __builtin_amdgcn_sched_barrier(0);
        short8 af[4], bf[4];
        #pragma unroll
        for (int rt = 0; rt < 4; rt++)
          af[rt] = *(const short8*)(AsBase(buf) + roA[rt] + quad * 64);
        #pragma unroll
        for (int ct = 0; ct < 4; ct++)
          bf[ct] = *(const short8*)(BsBase(buf) + roB[ct] + quad * 64);
        #pragma unroll
        for (int rt = 0; rt < 4; rt++)
          #pragma unroll
          for (int ct = 0; ct < 4; ct++)
            acc[rt][ct] = __builtin_amdgcn_mfma_f32_16x16x32_bf16(af[rt], bf[ct],
                                                                  acc[rt][ct], 0, 0, 0);
        __builtin_amdgcn_sched_barrier(0);
        __builtin_amdgcn_s_barrier();
      }

      // ---- epilogue A: orientation (n,m) ---------------------------------
      #pragma unroll
      for (int rt = 0; rt < 4; rt++) {
        int rbase = wr * 64 + rt * 16 + quad * 4;
        #pragma unroll
        for (int g = 0; g < 4; g++) {
          int r = rbase + g;
          int n = n0 + r;
          int bs = (n / 10) * 10;
          #pragma unroll
          for (int ct = 0; ct < 4; ct++) {
            int c = wc * 64 + ct * 16 + l16;
            int m = m0 + c;
            float R = acc[rt][ct][g] * 0.125f;
            float eR = __expf(R);
            bool sel = (R > 0.75f);
            bool zz = (m >= bs) & (m < bs + 9) & (m != n);
            float ef = zz ? 1.0f : eR;            // exp(0)=1
            S[r * 128 + (((c >> 3) ^ quad) << 3) + (c & 7)] = f2b(sel ? ef : -ef);
          }
        }
      }
      __syncthreads();
      {
        int r2b = wv * 32 + (lane >> 4);
        int s_ = lane & 15;
        #pragma unroll
        for (int i = 0; i < 8; i++) {
          int r2 = r2b + i * 4;
          int k = s_ ^ ((r2 >> 2) & 3);
          short8 vvv = *(const short8*)&S[r2 * 128 + s_ * 8];
          *(short8*)(Rg + (size_t)(n0 + r2) * NN + m0 + k * 8) = vvv;
        }
      }
      if (bi != bj) {
        // ---- epilogue B: orientation (m,n) -------------------------------
        __syncthreads();
        #pragma unroll
        for (int rt = 0; rt < 4; rt++) {
          int rbase = wr * 64 + rt * 16 + quad * 4;
          #pragma unroll
          for (int g = 0; g < 4; g++) {
            int r = rbase + g;
            int n = n0 + r;
            #pragma unroll
            for (int ct = 0; ct < 4; ct++) {
              int c = wc * 64 + ct * 16 + l16;
              int m = m0 + c;
              int bsm = (m / 10) * 10;
              float R = acc[rt][ct][g] * 0.125f;
              float eR = __expf(R);
              bool sel = (R > 0.75f);
              bool zz = (n >= bsm) & (n < bsm + 9) & (m != n);
              float ef = zz ? 1.0f : eR;
              S[c * 128 + (((r >> 3) ^ l16) << 3) + (r & 7)] = f2b(sel ? ef : -ef);
            }
          }
        }
        __syncthreads();
        int r2b = wv * 32 + (lane >> 4);
        int s_ = lane & 15;
        #pragma unroll
        for (int i = 0; i < 8; i++) {
          int r2 = r2b + i * 4;
          int k = s_ ^ (r2 & 15);
          short8 vvv = *(const short8*)&S[r2 * 128 + s_ * 8];
          *(short8*)(Rg + (size_t)(m0 + r2) * NN + n0 + k * 8) = vvv;
        }
      }
      __syncthreads();
      #undef AsBase
      #undef BsBase
    }
  }
  if (phase == 7) { __threadfence(); cg::this_grid().sync(); }

  // ===================== phase F: sm rows + X tiles (units 0..1199) ========
  if (phase & 4) {
    for (int u = (int)blockIdx.x; u < 1200; u += nb) {
      if (u < 800) {
        // ---- softmax rows: n = u*4 + wave --------------------------------
        int w = tid >> 6;
        int n = u * 4 + w;
        const unsigned short* rp = Rg + (size_t)n * NN;
        short8 s[7];
        float z = 0.f, e = 0.f;
        #pragma unroll
        for (int i = 0; i < 7; i++) {
          int c = lane + i * 64;
          if (c < 400) {
            s[i] = *(const short8*)(rp + c * 8);
            #pragma unroll
            for (int j = 0; j < 8; j++) {
              float val = b2f((unsigned short)s[i][j]);
              z += fabsf(val);
              e += fmaxf(val, 0.f);
            }
          }
        }
        #pragma unroll
        for (int off = 1; off <= 32; off <<= 1) {
          z += __shfl_xor(z, off, 64);
          e += __shfl_xor(e, off, 64);
        }
        float rd = 1.0f / (e + 1e-8f * z);
        float* op = out2 + (size_t)n * NN;
        #pragma unroll
        for (int i = 0; i < 7; i++) {
          int c = lane + i * 64;
          if (c < 400) {
            f32x4 o0, o1;
            #pragma unroll
            for (int j = 0; j < 4; j++) {
              float a = b2f((unsigned short)s[i][j]);
              o0[j] = (a > 0.f) ? a * rd : 0.f;
              float b = b2f((unsigned short)s[i][4 + j]);
              o1[j] = (b > 0.f) ? b * rd : 0.f;
            }
            __builtin_nontemporal_store(o0, (f32x4*)(op + c * 8));
            __builtin_nontemporal_store(o1, (f32x4*)(op + c * 8 + 4));
          }
        }
      } else {
        // ---- X tiles: X_h[n][d] = vn.(G0+G1) - zone correction -----------
        int xb = u - 800;
        unsigned short* Sz = S;                 // [4][16][48]
        int hl = tid >> 6;
        int h  = (xb & 1) * 4 + hl;
        int n0 = (xb >> 1) * 16;
        int lo = (n0 / 10) * 10;                // zone window [lo, lo+32)
        __syncthreads();                        // protect S reuse across units

        short8 aZ[2];
        #pragma unroll
        for (int kh = 0; kh < 2; kh++)
          aZ[kh] = *(const short8*)(vnfull + (size_t)(n0 + l16) * CC + h * DH + kh * 32 + quad * 8);

        #pragma unroll
        for (int ct = 0; ct < 2; ct++) {
          int rB = lo + ct * 16 + l16;
          int rC = rB < NN ? rB : NN - 1;       // clamp OOB (mask kills it)
          short8 b0 = *(const short8*)(vnfull + (size_t)rC * CC + h * DH + quad * 8);
          short8 b1 = *(const short8*)(vnfull + (size_t)rC * CC + h * DH + 32 + quad * 8);
          f32x4 cS = (f32x4){0.f, 0.f, 0.f, 0.f};
          cS = __builtin_amdgcn_mfma_f32_16x16x32_bf16(aZ[0], b0, cS, 0, 0, 0);
          cS = __builtin_amdgcn_mfma_f32_16x16x32_bf16(aZ[1], b1, cS, 0, 0, 0);
          int m = lo + ct * 16 + l16;
          #pragma unroll
          for (int g = 0; g < 4; g++) {
            int n = n0 + quad * 4 + g;
            int bs = (n / 10) * 10;
            bool keep = (m >= bs) & (m < bs + 9) & (m != n);
            Sz[(hl * 16 + quad * 4 + g) * 48 + ct * 16 + l16] = f2b(keep ? -cS[g] : 0.f);
          }
        }
        __syncthreads();

        f32x4 xr[4];
        #pragma unroll
        for (int nt = 0; nt < 4; nt++) {
          const float* gp = Gf + (size_t)h * 4096 + (nt * 16 + l16) * 64 + quad * 8;
          f32x4 lo0 = *(const f32x4*)gp        + *(const f32x4*)(gp + 32768);
          f32x4 hi0 = *(const f32x4*)(gp + 4)  + *(const f32x4*)(gp + 4 + 32768);
          f32x4 lo1 = *(const f32x4*)(gp + 32) + *(const f32x4*)(gp + 32 + 32768);
          f32x4 hi1 = *(const f32x4*)(gp + 36) + *(const f32x4*)(gp + 36 + 32768);
          short8 g0 = pack8(lo0, hi0);
          short8 g1 = pack8(lo1, hi1);
          f32x4 cX = (f32x4){0.f, 0.f, 0.f, 0.f};
          cX = __builtin_amdgcn_mfma_f32_16x16x32_bf16(aZ[0], g0, cX, 0, 0, 0);
          cX = __builtin_amdgcn_mfma_f32_16x16x32_bf16(aZ[1], g1, cX, 0, 0, 0);
          xr[nt] = cX;
        }

        short8 aC = *(const short8*)&Sz[(hl * 16 + l16) * 48 + quad * 8];
        #pragma unroll
        for (int nt = 0; nt < 4; nt++) {
          short8 b = *(const short8*)(vT + (size_t)(h * DH + nt * 16 + l16) * NN + lo + quad * 8);
          xr[nt] = __builtin_amdgcn_mfma_f32_16x16x32_bf16(aC, b, xr[nt], 0, 0, 0);
        }

        #pragma unroll
        for (int nt = 0; nt < 4; nt++)
          #pragma unroll
          for (int g = 0; g < 4; g++)
            __builtin_nontemporal_store(xr[nt][g],
                out + (size_t)(n0 + quad * 4 + g) * (2 * CC) + h * DH + nt * 16 + l16);
        __syncthreads();
      }
    }
  }
}

// ---------------------------------------------------------------------------
extern "C" void kernel_launch(void* const* d_in, const int* in_sizes, int n_in,
                              void* d_out, int out_size, void* d_ws, size_t ws_size,
                              hipStream_t stream) {
  const float* v = (const float*)d_in[1];   // only live input
  float* out = (float*)d_out;

  // ws carve (~31 MB): [Gf 2x32768] f32, [vnfull][vT][vnT] bf16, [Rg] bf16
  float* Gf = (float*)d_ws;
  unsigned short* vnfull = (unsigned short*)(Gf + 2 * HEADS * DH * DH);
  unsigned short* vT  = vnfull + (size_t)NN * CC;
  unsigned short* vnT = vT + (size_t)NN * CC;
  unsigned short* Rg  = vnT + (size_t)NN * CC;
  float* out2 = out + (size_t)NN * 2 * CC;

  int phase_all = 7;
  void* args[] = {(void*)&v, (void*)&vnfull, (void*)&vT, (void*)&vnT,
                  (void*)&Gf, (void*)&Rg, (void*)&out2, (void*)&out,
                  (void*)&phase_all};
  hipError_t err = hipLaunchCooperativeKernel((void*)k_all, dim3(1024), dim3(256),
                                              args, 0, stream);
  if (err != hipSuccess) {
    // fallback: same kernel as 3 ordinary dispatches (phase-masked, no grid.sync)
    k_all<<<dim3(400),  dim3(256), 0, stream>>>(v, vnfull, vT, vnT, Gf, Rg, out2, out, 1);
    k_all<<<dim3(341),  dim3(256), 0, stream>>>(v, vnfull, vT, vnT, Gf, Rg, out2, out, 2);
    k_all<<<dim3(1200), dim3(256), 0, stream>>>(v, vnfull, vT, vnT, Gf, Rg, out2, out, 4);
  }
}

// Round 8
// 143.753 us; speedup vs baseline: 4.3656x; 4.3656x over previous
//
#include <hip/hip_runtime.h>

// Attention_msa_TwoStream. Only v_cls (d_in[1]) feeds outputs (MLP/q/k dead).
// N=3200, H=8, d=64, C=512; fp32 I/O; bf16 MFMA internals.
// Pipeline (4 dispatches): memset(Gf) -> k_prep (norms + vT + x_ori + G_h)
// -> k_rgemm (R=1/8 vn.vn^T, SYMMETRIC: 325 upper-tri 128x128 tiles, BK=32
//    counted-vmcnt 2-deep pipeline; epilogue stages through the dead 32 KB
//    LDS dbuf and writes both (bi,bj) and (bj,bi) tiles as full 256B rows)
// -> k_fused (rows: Z/E row-sum + normalize -> out2 | tiles: X = vn.G - corr).
// Rg is stored/loaded temporal (rides Infinity Cache between dispatches).
// [Session-best configuration: measured 144.7 us. Fusion (r7), no-LDS (r5),
//  64x64 tiles (r6), 4-buf pipeline (r4) all measured worse; reverted.]

#define NN 3200
#define HEADS 8
#define DH 64
#define CC 512

typedef __attribute__((ext_vector_type(8))) short short8;   // 8 bf16
typedef __attribute__((ext_vector_type(4))) float f32x4;

static __device__ __forceinline__ unsigned short f2b(float f) {
  union { float f; unsigned u; } x; x.f = f;
  unsigned r = x.u + 0x7FFFu + ((x.u >> 16) & 1u);   // RTN-even
  return (unsigned short)(r >> 16);
}
static __device__ __forceinline__ float b2f(unsigned short s) {
  union { unsigned u; float f; } x; x.u = ((unsigned)s) << 16; return x.f;
}
static __device__ __forceinline__ short8 pack8(f32x4 lo, f32x4 hi) {
  short8 r;
  r[0] = (short)f2b(lo[0]); r[1] = (short)f2b(lo[1]);
  r[2] = (short)f2b(lo[2]); r[3] = (short)f2b(lo[3]);
  r[4] = (short)f2b(hi[0]); r[5] = (short)f2b(hi[1]);
  r[6] = (short)f2b(hi[2]); r[7] = (short)f2b(hi[3]);
  return r;
}

typedef const void __attribute__((address_space(1))) gvoid_t;
typedef void __attribute__((address_space(3))) lvoid_t;
static __device__ __forceinline__ void gl_lds16(const void* g, void* l) {
  __builtin_amdgcn_global_load_lds((gvoid_t*)g, (lvoid_t*)l, 16, 0, 0);
}

// ---------------------------------------------------------------------------
// k_prep: per-(n,h) L2 norm; writes vnfull bf16 (cached - heavy reuse),
// vT bf16 + x_ori f32 (non-temporal - streaming), G_h accum via MFMA+atomics.
__global__ __launch_bounds__(256) void k_prep(const float* __restrict__ v,
                                              unsigned short* __restrict__ vnfull,
                                              unsigned short* __restrict__ vT,
                                              float* __restrict__ Gf,
                                              float* __restrict__ out) {
  __shared__ unsigned short tileV[DH][72];   // [dim][row]
  __shared__ unsigned short tileN[DH][72];
  int h  = blockIdx.x & 7;
  int n0 = (int)(blockIdx.x >> 3) * 64;
  int j  = threadIdx.x & 63;       // dim within head
  int w  = threadIdx.x >> 6;       // wave = row group
  #pragma unroll
  for (int i = 0; i < 16; i++) {
    int n = n0 + w * 16 + i;
    float val = v[(size_t)n * CC + h * DH + j];
    float ss = val * val;
    #pragma unroll
    for (int off = 32; off >= 1; off >>= 1) ss += __shfl_xor(ss, off, 64);
    float inv = 1.0f / (sqrtf(ss) + 1e-8f);
    unsigned short un = f2b(val * inv);
    tileV[j][w * 16 + i] = f2b(val);
    tileN[j][w * 16 + i] = un;
    vnfull[(size_t)n * CC + h * DH + j] = un;
    __builtin_nontemporal_store(val, out + (size_t)n * (2 * CC) + CC + h * DH + j);
  }
  __syncthreads();
  #pragma unroll
  for (int i = 0; i < 16; i++) {
    int jj = w * 16 + i;
    __builtin_nontemporal_store(tileV[jj][j], vT + ((size_t)h * DH + jj) * NN + n0 + j);
  }
  // G_h partial: G[d][k] += sum_{m in tile} V[m][d]*vn[m][k]
  int lane = threadIdx.x & 63, quad = lane >> 4, l16 = lane & 15;
  short8 aV[2];
  #pragma unroll
  for (int kh = 0; kh < 2; kh++)
    aV[kh] = *(const short8*)&tileV[w * 16 + l16][kh * 32 + quad * 8];
  #pragma unroll
  for (int ct = 0; ct < 4; ct++) {
    f32x4 g4 = (f32x4){0.f, 0.f, 0.f, 0.f};
    #pragma unroll
    for (int kh = 0; kh < 2; kh++) {
      short8 bN = *(const short8*)&tileN[ct * 16 + l16][kh * 32 + quad * 8];
      g4 = __builtin_amdgcn_mfma_f32_16x16x32_bf16(aV[kh], bN, g4, 0, 0, 0);
    }
    #pragma unroll
    for (int g = 0; g < 4; g++)
      atomicAdd(&Gf[(size_t)h * 4096 + (w * 16 + quad * 4 + g) * 64 + ct * 16 + l16], g4[g]);
  }
}

// ---------------------------------------------------------------------------
// k_rgemm: R = (1/8) vnfull.vnfull^T, symmetric -> only 325 upper-tri tiles.
// K-loop: BK=32 dbuf with counted s_waitcnt vmcnt(4) + raw s_barrier so the
// prefetch global_load_lds stays in flight under the MFMAs (no vmcnt(0)
// drain). Epilogue: transform(acc,n,m) -> LDS -> coalesced (bi,bj) write;
// for bi!=bj additionally transform(acc,m,n) -> transposed LDS staging ->
// coalesced (bj,bi) write. Zone mask is uniform (auto-false for |n-m|>=10).
// grid 325.
__global__ __launch_bounds__(256) void k_rgemm(const unsigned short* __restrict__ vnfull,
                                               unsigned short* __restrict__ Rg) {
  __shared__ __align__(16) unsigned short S[16384];   // 32 KB: As/Bs dbuf, then tile
  #define AsBase(buf) (S + (buf) * 4096)
  #define BsBase(buf) (S + 8192 + (buf) * 4096)
  // upper-triangular (incl. diagonal) tile map: bid -> (bi, bj), bj >= bi
  int bid = (int)blockIdx.x, bi = 0;
  while (bid >= 25 - bi) { bid -= 25 - bi; bi++; }
  int bj = bi + bid;
  int n0 = bi * 128, m0 = bj * 128;
  int tid = threadIdx.x;
  int wv = tid >> 6, wr = wv >> 1, wc = wv & 1;
  int lane = tid & 63, quad = lane >> 4, l16 = lane & 15;

  const unsigned short* aG[2];
  const unsigned short* bG[2];
  int sl[2];
  #pragma unroll
  for (int t = 0; t < 2; t++) {
    int s = tid + t * 256;
    sl[t] = s;
    int row = ((s >> 5) << 3) | (s & 7), kc = (s >> 3) & 3;
    aG[t] = vnfull + (size_t)(n0 + row) * CC + kc * 8;
    bG[t] = vnfull + (size_t)(m0 + row) * CC + kc * 8;
  }

  int roA[4], roB[4];
  #pragma unroll
  for (int rt = 0; rt < 4; rt++) {
    int row = wr * 64 + rt * 16 + l16;
    roA[rt] = (row >> 3) * 256 + (row & 7) * 8;
  }
  #pragma unroll
  for (int ct = 0; ct < 4; ct++) {
    int row = wc * 64 + ct * 16 + l16;
    roB[ct] = (row >> 3) * 256 + (row & 7) * 8;
  }

  f32x4 acc[4][4];
  #pragma unroll
  for (int rt = 0; rt < 4; rt++)
    #pragma unroll
    for (int ct = 0; ct < 4; ct++) acc[rt][ct] = (f32x4){0.f, 0.f, 0.f, 0.f};

  #pragma unroll
  for (int t = 0; t < 2; t++) gl_lds16(aG[t], AsBase(0) + sl[t] * 8);
  #pragma unroll
  for (int t = 0; t < 2; t++) gl_lds16(bG[t], BsBase(0) + sl[t] * 8);

  #pragma unroll 1
  for (int kk = 0; kk < 16; kk++) {
    int buf = kk & 1;
    if (kk < 15) {
      int ko = (kk + 1) * 32;
      #pragma unroll
      for (int t = 0; t < 2; t++) gl_lds16(aG[t] + ko, AsBase(buf ^ 1) + sl[t] * 8);
      #pragma unroll
      for (int t = 0; t < 2; t++) gl_lds16(bG[t] + ko, BsBase(buf ^ 1) + sl[t] * 8);
      asm volatile("s_waitcnt vmcnt(4)" ::: "memory");  // oldest 4 (this buf) done
    } else {
      asm volatile("s_waitcnt vmcnt(0)" ::: "memory");  // last tile: drain
    }
    __builtin_amdgcn_s_barrier();            // all waves' buf populated
    __builtin_amdgcn_sched_barrier(0);
    short8 af[4], bf[4];
    #pragma unroll
    for (int rt = 0; rt < 4; rt++)
      af[rt] = *(const short8*)(AsBase(buf) + roA[rt] + quad * 64);
    #pragma unroll
    for (int ct = 0; ct < 4; ct++)
      bf[ct] = *(const short8*)(BsBase(buf) + roB[ct] + quad * 64);
    #pragma unroll
    for (int rt = 0; rt < 4; rt++)
      #pragma unroll
      for (int ct = 0; ct < 4; ct++)
        acc[rt][ct] = __builtin_amdgcn_mfma_f32_16x16x32_bf16(af[rt], bf[ct],
                                                              acc[rt][ct], 0, 0, 0);
    __builtin_amdgcn_sched_barrier(0);
    __builtin_amdgcn_s_barrier();            // all waves done reading buf
  }

  // ---- epilogue A: orientation (n,m) — swizzled LDS stage + row writes ---
  // Tile element (r,c) at S[r*128 + ((c>>3)^quad)*8 + (c&7)], quad==(r>>2)&3.
  #pragma unroll
  for (int rt = 0; rt < 4; rt++) {
    int rbase = wr * 64 + rt * 16 + quad * 4;
    #pragma unroll
    for (int g = 0; g < 4; g++) {
      int r = rbase + g;
      int n = n0 + r;
      int bs = (n / 10) * 10;
      #pragma unroll
      for (int ct = 0; ct < 4; ct++) {
        int c = wc * 64 + ct * 16 + l16;
        int m = m0 + c;
        float R = acc[rt][ct][g] * 0.125f;
        float eR = __expf(R);
        bool sel = (R > 0.75f);
        bool zz = (m >= bs) & (m < bs + 9) & (m != n);
        float ef = zz ? 1.0f : eR;            // exp(0)=1
        S[r * 128 + (((c >> 3) ^ quad) << 3) + (c & 7)] = f2b(sel ? ef : -ef);
      }
    }
  }
  __syncthreads();
  {
    int r2b = wv * 32 + (lane >> 4);
    int s_ = lane & 15;
    #pragma unroll
    for (int i = 0; i < 8; i++) {
      int r2 = r2b + i * 4;
      int k = s_ ^ ((r2 >> 2) & 3);
      short8 vvv = *(const short8*)&S[r2 * 128 + s_ * 8];
      *(short8*)(Rg + (size_t)(n0 + r2) * NN + m0 + k * 8) = vvv;   // temporal: ride L3
    }
  }

  if (bi != bj) {
    // ---- epilogue B: orientation (m,n) — transposed staging --------------
    // Element (r,c) -> S[c*128 + ((r>>3)^l16)*8 + (r&7)], l16 == c&15.
    __syncthreads();
    #pragma unroll
    for (int rt = 0; rt < 4; rt++) {
      int rbase = wr * 64 + rt * 16 + quad * 4;
      #pragma unroll
      for (int g = 0; g < 4; g++) {
        int r = rbase + g;
        int n = n0 + r;
        #pragma unroll
        for (int ct = 0; ct < 4; ct++) {
          int c = wc * 64 + ct * 16 + l16;
          int m = m0 + c;
          int bsm = (m / 10) * 10;
          float R = acc[rt][ct][g] * 0.125f;
          float eR = __expf(R);
          bool sel = (R > 0.75f);
          bool zz = (n >= bsm) & (n < bsm + 9) & (m != n);
          float ef = zz ? 1.0f : eR;
          S[c * 128 + (((r >> 3) ^ l16) << 3) + (r & 7)] = f2b(sel ? ef : -ef);
        }
      }
    }
    __syncthreads();
    int r2b = wv * 32 + (lane >> 4);
    int s_ = lane & 15;
    #pragma unroll
    for (int i = 0; i < 8; i++) {
      int r2 = r2b + i * 4;                  // output row = m0 + r2
      int k = s_ ^ (r2 & 15);
      short8 vvv = *(const short8*)&S[r2 * 128 + s_ * 8];
      *(short8*)(Rg + (size_t)(m0 + r2) * NN + n0 + k * 8) = vvv;
    }
  }
  #undef AsBase
  #undef BsBase
}

// ---------------------------------------------------------------------------
// k_fused: blocks [0,800): out2 rows (wave-per-row Z/E sum + normalize);
//          blocks [800,1200): k_x tiles (X = vn.G - zone corr).
__global__ __launch_bounds__(256) void k_fused(const unsigned short* __restrict__ Rg,
                                               const unsigned short* __restrict__ vnfull,
                                               const float* __restrict__ Gf,
                                               const unsigned short* __restrict__ vT,
                                               float* __restrict__ out2,
                                               float* __restrict__ out) {
  int bid = (int)blockIdx.x;
  if (bid < 800) {
    // ---- softmax rows: n = bid*4 + wave ---------------------------------
    int w = threadIdx.x >> 6, lane = threadIdx.x & 63;
    int n = bid * 4 + w;
    const unsigned short* rp = Rg + (size_t)n * NN;
    short8 s[7];
    float z = 0.f, e = 0.f;
    #pragma unroll
    for (int i = 0; i < 7; i++) {
      int c = lane + i * 64;              // chunk of 8 bf16; 400 chunks/row
      if (c < 400) {
        s[i] = *(const short8*)(rp + c * 8);   // temporal: L3 hit after k_rgemm
        #pragma unroll
        for (int j = 0; j < 8; j++) {
          float val = b2f((unsigned short)s[i][j]);
          z += fabsf(val);
          e += fmaxf(val, 0.f);
        }
      }
    }
    #pragma unroll
    for (int off = 1; off <= 32; off <<= 1) {
      z += __shfl_xor(z, off, 64);
      e += __shfl_xor(e, off, 64);
    }
    float rd = 1.0f / (e + 1e-8f * z);
    float* op = out2 + (size_t)n * NN;
    #pragma unroll
    for (int i = 0; i < 7; i++) {
      int c = lane + i * 64;
      if (c < 400) {
        f32x4 o0, o1;
        #pragma unroll
        for (int j = 0; j < 4; j++) {
          float a = b2f((unsigned short)s[i][j]);
          o0[j] = (a > 0.f) ? a * rd : 0.f;
          float b = b2f((unsigned short)s[i][4 + j]);
          o1[j] = (b > 0.f) ? b * rd : 0.f;
        }
        __builtin_nontemporal_store(o0, (f32x4*)(op + c * 8));
        __builtin_nontemporal_store(o1, (f32x4*)(op + c * 8 + 4));
      }
    }
  } else {
    // ---- X tiles: X_h[n][d] = vn.G - zone correction --------------------
    bid -= 800;
    __shared__ __align__(16) unsigned short Sz[4][16][48];
    int hl   = threadIdx.x >> 6;
    int h    = (bid & 1) * 4 + hl;
    int lane = threadIdx.x & 63;
    int quad = lane >> 4, l16 = lane & 15;
    int n0 = (bid >> 1) * 16;
    int lo = (n0 / 10) * 10;                    // zone window [lo, lo+32)

    short8 aZ[2];
    #pragma unroll
    for (int kh = 0; kh < 2; kh++)
      aZ[kh] = *(const short8*)(vnfull + (size_t)(n0 + l16) * CC + h * DH + kh * 32 + quad * 8);

    #pragma unroll
    for (int ct = 0; ct < 2; ct++) {
      int rB = lo + ct * 16 + l16;
      int rC = rB < NN ? rB : NN - 1;           // clamp OOB (mask kills it)
      short8 b0 = *(const short8*)(vnfull + (size_t)rC * CC + h * DH + quad * 8);
      short8 b1 = *(const short8*)(vnfull + (size_t)rC * CC + h * DH + 32 + quad * 8);
      f32x4 cS = (f32x4){0.f, 0.f, 0.f, 0.f};
      cS = __builtin_amdgcn_mfma_f32_16x16x32_bf16(aZ[0], b0, cS, 0, 0, 0);
      cS = __builtin_amdgcn_mfma_f32_16x16x32_bf16(aZ[1], b1, cS, 0, 0, 0);
      int m = lo + ct * 16 + l16;
      #pragma unroll
      for (int g = 0; g < 4; g++) {
        int n = n0 + quad * 4 + g;
        int bs = (n / 10) * 10;
        bool keep = (m >= bs) & (m < bs + 9) & (m != n);
        Sz[hl][quad * 4 + g][ct * 16 + l16] = f2b(keep ? -cS[g] : 0.f);
      }
    }
    __syncthreads();

    f32x4 xr[4];
    #pragma unroll
    for (int nt = 0; nt < 4; nt++) {
      const float* gp = Gf + (size_t)h * 4096 + (nt * 16 + l16) * 64 + quad * 8;
      short8 g0 = pack8(*(const f32x4*)gp, *(const f32x4*)(gp + 4));
      short8 g1 = pack8(*(const f32x4*)(gp + 32), *(const f32x4*)(gp + 36));
      f32x4 cX = (f32x4){0.f, 0.f, 0.f, 0.f};
      cX = __builtin_amdgcn_mfma_f32_16x16x32_bf16(aZ[0], g0, cX, 0, 0, 0);
      cX = __builtin_amdgcn_mfma_f32_16x16x32_bf16(aZ[1], g1, cX, 0, 0, 0);
      xr[nt] = cX;
    }

    short8 aC = *(const short8*)&Sz[hl][l16][quad * 8];
    #pragma unroll
    for (int nt = 0; nt < 4; nt++) {
      short8 b = *(const short8*)(vT + (size_t)(h * DH + nt * 16 + l16) * NN + lo + quad * 8);
      xr[nt] = __builtin_amdgcn_mfma_f32_16x16x32_bf16(aC, b, xr[nt], 0, 0, 0);
    }

    #pragma unroll
    for (int nt = 0; nt < 4; nt++)
      #pragma unroll
      for (int g = 0; g < 4; g++)
        __builtin_nontemporal_store(xr[nt][g],
            out + (size_t)(n0 + quad * 4 + g) * (2 * CC) + h * DH + nt * 16 + l16);
  }
}

// ---------------------------------------------------------------------------
extern "C" void kernel_launch(void* const* d_in, const int* in_sizes, int n_in,
                              void* d_out, int out_size, void* d_ws, size_t ws_size,
                              hipStream_t stream) {
  const float* v = (const float*)d_in[1];   // only live input
  float* out = (float*)d_out;

  // ws carve (~27 MB): [Gf 32768] f32, [vnfull][vT] bf16, [Rg] bf16
  float* Gf = (float*)d_ws;
  unsigned short* vnfull = (unsigned short*)(Gf + HEADS * DH * DH);
  unsigned short* vT = vnfull + (size_t)NN * CC;
  unsigned short* Rg = vT + (size_t)NN * CC;

  hipMemsetAsync(Gf, 0, HEADS * DH * DH * sizeof(float), stream);
  k_prep<<<dim3(HEADS * (NN / 64)), dim3(256), 0, stream>>>(v, vnfull, vT, Gf, out);
  k_rgemm<<<dim3(325), dim3(256), 0, stream>>>(vnfull, Rg);   // upper-tri tiles
  k_fused<<<dim3(800 + (NN / 16) * 2), dim3(256), 0, stream>>>(
      Rg, vnfull, Gf, vT, out + (size_t)NN * 2 * CC, out);
}

// Round 9
// 142.974 us; speedup vs baseline: 4.3894x; 1.0055x over previous
//
#include <hip/hip_runtime.h>

// Attention_msa_TwoStream. Only v_cls (d_in[1]) feeds outputs (MLP/q/k dead).
// N=3200, H=8, d=64, C=512; fp32 I/O; bf16 MFMA internals.
// Pipeline (4 dispatches): memset(Gf) -> k_prep (norms + vT + x_ori + G_h)
// -> k_rgemm (R=1/8 vn.vn^T, SYMMETRIC: 325 upper-tri 128x128 tiles, BK=32
//    counted-vmcnt dbuf; 512 threads / 8 waves per block (r8 had 4) to lift
//    TLP 1.27->2.54 waves/SIMD on the latency-bound K-loop; epilogue stages
//    via LDS -> full 256B coalesced rows, both orientations)
// -> k_fused (rows: Z/E row-sum + normalize -> out2 | tiles: X = vn.G - corr).
// Cost model (r7 calibration): ~97us fixed harness overhead in timed window;
// controllable = prep ~5 + rgemm ~30 + fused ~12. This round targets rgemm.

#define NN 3200
#define HEADS 8
#define DH 64
#define CC 512

typedef __attribute__((ext_vector_type(8))) short short8;   // 8 bf16
typedef __attribute__((ext_vector_type(4))) float f32x4;

static __device__ __forceinline__ unsigned short f2b(float f) {
  union { float f; unsigned u; } x; x.f = f;
  unsigned r = x.u + 0x7FFFu + ((x.u >> 16) & 1u);   // RTN-even
  return (unsigned short)(r >> 16);
}
static __device__ __forceinline__ float b2f(unsigned short s) {
  union { unsigned u; float f; } x; x.u = ((unsigned)s) << 16; return x.f;
}
static __device__ __forceinline__ short8 pack8(f32x4 lo, f32x4 hi) {
  short8 r;
  r[0] = (short)f2b(lo[0]); r[1] = (short)f2b(lo[1]);
  r[2] = (short)f2b(lo[2]); r[3] = (short)f2b(lo[3]);
  r[4] = (short)f2b(hi[0]); r[5] = (short)f2b(hi[1]);
  r[6] = (short)f2b(hi[2]); r[7] = (short)f2b(hi[3]);
  return r;
}

typedef const void __attribute__((address_space(1))) gvoid_t;
typedef void __attribute__((address_space(3))) lvoid_t;
static __device__ __forceinline__ void gl_lds16(const void* g, void* l) {
  __builtin_amdgcn_global_load_lds((gvoid_t*)g, (lvoid_t*)l, 16, 0, 0);
}

// ---------------------------------------------------------------------------
// k_prep: per-(n,h) L2 norm; writes vnfull bf16 (cached - heavy reuse),
// vT bf16 + x_ori f32 (non-temporal - streaming), G_h accum via MFMA+atomics.
__global__ __launch_bounds__(256) void k_prep(const float* __restrict__ v,
                                              unsigned short* __restrict__ vnfull,
                                              unsigned short* __restrict__ vT,
                                              float* __restrict__ Gf,
                                              float* __restrict__ out) {
  __shared__ unsigned short tileV[DH][72];   // [dim][row]
  __shared__ unsigned short tileN[DH][72];
  int h  = blockIdx.x & 7;
  int n0 = (int)(blockIdx.x >> 3) * 64;
  int j  = threadIdx.x & 63;       // dim within head
  int w  = threadIdx.x >> 6;       // wave = row group
  #pragma unroll
  for (int i = 0; i < 16; i++) {
    int n = n0 + w * 16 + i;
    float val = v[(size_t)n * CC + h * DH + j];
    float ss = val * val;
    #pragma unroll
    for (int off = 32; off >= 1; off >>= 1) ss += __shfl_xor(ss, off, 64);
    float inv = 1.0f / (sqrtf(ss) + 1e-8f);
    unsigned short un = f2b(val * inv);
    tileV[j][w * 16 + i] = f2b(val);
    tileN[j][w * 16 + i] = un;
    vnfull[(size_t)n * CC + h * DH + j] = un;
    __builtin_nontemporal_store(val, out + (size_t)n * (2 * CC) + CC + h * DH + j);
  }
  __syncthreads();
  #pragma unroll
  for (int i = 0; i < 16; i++) {
    int jj = w * 16 + i;
    __builtin_nontemporal_store(tileV[jj][j], vT + ((size_t)h * DH + jj) * NN + n0 + j);
  }
  // G_h partial: G[d][k] += sum_{m in tile} V[m][d]*vn[m][k]
  int lane = threadIdx.x & 63, quad = lane >> 4, l16 = lane & 15;
  short8 aV[2];
  #pragma unroll
  for (int kh = 0; kh < 2; kh++)
    aV[kh] = *(const short8*)&tileV[w * 16 + l16][kh * 32 + quad * 8];
  #pragma unroll
  for (int ct = 0; ct < 4; ct++) {
    f32x4 g4 = (f32x4){0.f, 0.f, 0.f, 0.f};
    #pragma unroll
    for (int kh = 0; kh < 2; kh++) {
      short8 bN = *(const short8*)&tileN[ct * 16 + l16][kh * 32 + quad * 8];
      g4 = __builtin_amdgcn_mfma_f32_16x16x32_bf16(aV[kh], bN, g4, 0, 0, 0);
    }
    #pragma unroll
    for (int g = 0; g < 4; g++)
      atomicAdd(&Gf[(size_t)h * 4096 + (w * 16 + quad * 4 + g) * 64 + ct * 16 + l16], g4[g]);
  }
}

// ---------------------------------------------------------------------------
// k_rgemm: R = (1/8) vnfull.vnfull^T, symmetric -> only 325 upper-tri tiles.
// 512 threads / 8 waves: wave (wr,wc) owns rows wr*64..+64, cols wc*32..+32
// (acc[4][2], 8 MFMA/K-step). K-loop: BK=32 dbuf, each thread stages one 16B
// slot per buffer per step; counted s_waitcnt vmcnt(2) + raw s_barrier keeps
// the next-tile loads in flight under the MFMAs. Epilogues as in r8.
__global__ __launch_bounds__(512) void k_rgemm(const unsigned short* __restrict__ vnfull,
                                               unsigned short* __restrict__ Rg) {
  __shared__ __align__(16) unsigned short S[16384];   // 32 KB: As/Bs dbuf, then tile
  #define AsBase(buf) (S + (buf) * 4096)
  #define BsBase(buf) (S + 8192 + (buf) * 4096)
  // upper-triangular (incl. diagonal) tile map: bid -> (bi, bj), bj >= bi
  int bid = (int)blockIdx.x, bi = 0;
  while (bid >= 25 - bi) { bid -= 25 - bi; bi++; }
  int bj = bi + bid;
  int n0 = bi * 128, m0 = bj * 128;
  int tid = threadIdx.x;
  int wv = tid >> 6, wr = wv >> 2, wc = wv & 3;
  int lane = tid & 63, quad = lane >> 4, l16 = lane & 15;

  // staging: one 16B slot per thread (512 slots cover a 128x32 bf16 tile)
  int row = ((tid >> 5) << 3) | (tid & 7), kc = (tid >> 3) & 3;
  const unsigned short* aG = vnfull + (size_t)(n0 + row) * CC + kc * 8;
  const unsigned short* bG = vnfull + (size_t)(m0 + row) * CC + kc * 8;

  int roA[4], roB[2];
  #pragma unroll
  for (int rt = 0; rt < 4; rt++) {
    int rw = wr * 64 + rt * 16 + l16;
    roA[rt] = (rw >> 3) * 256 + (rw & 7) * 8;
  }
  #pragma unroll
  for (int ct = 0; ct < 2; ct++) {
    int rw = wc * 32 + ct * 16 + l16;
    roB[ct] = (rw >> 3) * 256 + (rw & 7) * 8;
  }

  f32x4 acc[4][2];
  #pragma unroll
  for (int rt = 0; rt < 4; rt++)
    #pragma unroll
    for (int ct = 0; ct < 2; ct++) acc[rt][ct] = (f32x4){0.f, 0.f, 0.f, 0.f};

  gl_lds16(aG, AsBase(0) + tid * 8);
  gl_lds16(bG, BsBase(0) + tid * 8);

  #pragma unroll 1
  for (int kk = 0; kk < 16; kk++) {
    int buf = kk & 1;
    if (kk < 15) {
      int ko = (kk + 1) * 32;
      gl_lds16(aG + ko, AsBase(buf ^ 1) + tid * 8);
      gl_lds16(bG + ko, BsBase(buf ^ 1) + tid * 8);
      asm volatile("s_waitcnt vmcnt(2)" ::: "memory");  // this buf's 2 landed
    } else {
      asm volatile("s_waitcnt vmcnt(0)" ::: "memory");  // last tile: drain
    }
    __builtin_amdgcn_s_barrier();            // all waves' buf populated
    __builtin_amdgcn_sched_barrier(0);
    short8 af[4], bf[2];
    #pragma unroll
    for (int rt = 0; rt < 4; rt++)
      af[rt] = *(const short8*)(AsBase(buf) + roA[rt] + quad * 64);
    #pragma unroll
    for (int ct = 0; ct < 2; ct++)
      bf[ct] = *(const short8*)(BsBase(buf) + roB[ct] + quad * 64);
    #pragma unroll
    for (int rt = 0; rt < 4; rt++)
      #pragma unroll
      for (int ct = 0; ct < 2; ct++)
        acc[rt][ct] = __builtin_amdgcn_mfma_f32_16x16x32_bf16(af[rt], bf[ct],
                                                              acc[rt][ct], 0, 0, 0);
    __builtin_amdgcn_sched_barrier(0);
    __builtin_amdgcn_s_barrier();            // all waves done reading buf
  }

  // ---- epilogue A: orientation (n,m) — swizzled LDS stage + row writes ---
  // Tile element (r,c) at S[r*128 + ((c>>3)^quad)*8 + (c&7)], quad==(r>>2)&3.
  #pragma unroll
  for (int rt = 0; rt < 4; rt++) {
    int rbase = wr * 64 + rt * 16 + quad * 4;
    #pragma unroll
    for (int g = 0; g < 4; g++) {
      int r = rbase + g;
      int n = n0 + r;
      int bs = (n / 10) * 10;
      #pragma unroll
      for (int ct = 0; ct < 2; ct++) {
        int c = wc * 32 + ct * 16 + l16;
        int m = m0 + c;
        float R = acc[rt][ct][g] * 0.125f;
        float eR = __expf(R);
        bool sel = (R > 0.75f);
        bool zz = (m >= bs) & (m < bs + 9) & (m != n);
        float ef = zz ? 1.0f : eR;            // exp(0)=1
        S[r * 128 + (((c >> 3) ^ quad) << 3) + (c & 7)] = f2b(sel ? ef : -ef);
      }
    }
  }
  __syncthreads();
  {
    int r2b = wv * 4 + (lane >> 4);          // [0,32)
    int s_ = lane & 15;
    #pragma unroll
    for (int i = 0; i < 4; i++) {
      int r2 = r2b + i * 32;
      int k = s_ ^ ((r2 >> 2) & 3);
      short8 vvv = *(const short8*)&S[r2 * 128 + s_ * 8];
      *(short8*)(Rg + (size_t)(n0 + r2) * NN + m0 + k * 8) = vvv;   // temporal: ride L3
    }
  }

  if (bi != bj) {
    // ---- epilogue B: orientation (m,n) — transposed staging --------------
    // Element (r,c) -> S[c*128 + ((r>>3)^l16)*8 + (r&7)], l16 == c&15.
    __syncthreads();
    #pragma unroll
    for (int rt = 0; rt < 4; rt++) {
      int rbase = wr * 64 + rt * 16 + quad * 4;
      #pragma unroll
      for (int g = 0; g < 4; g++) {
        int r = rbase + g;
        int n = n0 + r;
        #pragma unroll
        for (int ct = 0; ct < 2; ct++) {
          int c = wc * 32 + ct * 16 + l16;
          int m = m0 + c;
          int bsm = (m / 10) * 10;
          float R = acc[rt][ct][g] * 0.125f;
          float eR = __expf(R);
          bool sel = (R > 0.75f);
          bool zz = (n >= bsm) & (n < bsm + 9) & (m != n);
          float ef = zz ? 1.0f : eR;
          S[c * 128 + (((r >> 3) ^ l16) << 3) + (r & 7)] = f2b(sel ? ef : -ef);
        }
      }
    }
    __syncthreads();
    int r2b = wv * 4 + (lane >> 4);
    int s_ = lane & 15;
    #pragma unroll
    for (int i = 0; i < 4; i++) {
      int r2 = r2b + i * 32;                 // output row = m0 + r2
      int k = s_ ^ (r2 & 15);
      short8 vvv = *(const short8*)&S[r2 * 128 + s_ * 8];
      *(short8*)(Rg + (size_t)(m0 + r2) * NN + n0 + k * 8) = vvv;
    }
  }
  #undef AsBase
  #undef BsBase
}

// ---------------------------------------------------------------------------
// k_fused: blocks [0,800): out2 rows (wave-per-row Z/E sum + normalize);
//          blocks [800,1200): k_x tiles (X = vn.G - zone corr).
__global__ __launch_bounds__(256) void k_fused(const unsigned short* __restrict__ Rg,
                                               const unsigned short* __restrict__ vnfull,
                                               const float* __restrict__ Gf,
                                               const unsigned short* __restrict__ vT,
                                               float* __restrict__ out2,
                                               float* __restrict__ out) {
  int bid = (int)blockIdx.x;
  if (bid < 800) {
    // ---- softmax rows: n = bid*4 + wave ---------------------------------
    int w = threadIdx.x >> 6, lane = threadIdx.x & 63;
    int n = bid * 4 + w;
    const unsigned short* rp = Rg + (size_t)n * NN;
    short8 s[7];
    float z = 0.f, e = 0.f;
    #pragma unroll
    for (int i = 0; i < 7; i++) {
      int c = lane + i * 64;              // chunk of 8 bf16; 400 chunks/row
      if (c < 400) {
        s[i] = *(const short8*)(rp + c * 8);   // temporal: L3 hit after k_rgemm
        #pragma unroll
        for (int j = 0; j < 8; j++) {
          float val = b2f((unsigned short)s[i][j]);
          z += fabsf(val);
          e += fmaxf(val, 0.f);
        }
      }
    }
    #pragma unroll
    for (int off = 1; off <= 32; off <<= 1) {
      z += __shfl_xor(z, off, 64);
      e += __shfl_xor(e, off, 64);
    }
    float rd = 1.0f / (e + 1e-8f * z);
    float* op = out2 + (size_t)n * NN;
    #pragma unroll
    for (int i = 0; i < 7; i++) {
      int c = lane + i * 64;
      if (c < 400) {
        f32x4 o0, o1;
        #pragma unroll
        for (int j = 0; j < 4; j++) {
          float a = b2f((unsigned short)s[i][j]);
          o0[j] = (a > 0.f) ? a * rd : 0.f;
          float b = b2f((unsigned short)s[i][4 + j]);
          o1[j] = (b > 0.f) ? b * rd : 0.f;
        }
        __builtin_nontemporal_store(o0, (f32x4*)(op + c * 8));
        __builtin_nontemporal_store(o1, (f32x4*)(op + c * 8 + 4));
      }
    }
  } else {
    // ---- X tiles: X_h[n][d] = vn.G - zone correction --------------------
    bid -= 800;
    __shared__ __align__(16) unsigned short Sz[4][16][48];
    int hl   = threadIdx.x >> 6;
    int h    = (bid & 1) * 4 + hl;
    int lane = threadIdx.x & 63;
    int quad = lane >> 4, l16 = lane & 15;
    int n0 = (bid >> 1) * 16;
    int lo = (n0 / 10) * 10;                    // zone window [lo, lo+32)

    short8 aZ[2];
    #pragma unroll
    for (int kh = 0; kh < 2; kh++)
      aZ[kh] = *(const short8*)(vnfull + (size_t)(n0 + l16) * CC + h * DH + kh * 32 + quad * 8);

    #pragma unroll
    for (int ct = 0; ct < 2; ct++) {
      int rB = lo + ct * 16 + l16;
      int rC = rB < NN ? rB : NN - 1;           // clamp OOB (mask kills it)
      short8 b0 = *(const short8*)(vnfull + (size_t)rC * CC + h * DH + quad * 8);
      short8 b1 = *(const short8*)(vnfull + (size_t)rC * CC + h * DH + 32 + quad * 8);
      f32x4 cS = (f32x4){0.f, 0.f, 0.f, 0.f};
      cS = __builtin_amdgcn_mfma_f32_16x16x32_bf16(aZ[0], b0, cS, 0, 0, 0);
      cS = __builtin_amdgcn_mfma_f32_16x16x32_bf16(aZ[1], b1, cS, 0, 0, 0);
      int m = lo + ct * 16 + l16;
      #pragma unroll
      for (int g = 0; g < 4; g++) {
        int n = n0 + quad * 4 + g;
        int bs = (n / 10) * 10;
        bool keep = (m >= bs) & (m < bs + 9) & (m != n);
        Sz[hl][quad * 4 + g][ct * 16 + l16] = f2b(keep ? -cS[g] : 0.f);
      }
    }
    __syncthreads();

    f32x4 xr[4];
    #pragma unroll
    for (int nt = 0; nt < 4; nt++) {
      const float* gp = Gf + (size_t)h * 4096 + (nt * 16 + l16) * 64 + quad * 8;
      short8 g0 = pack8(*(const f32x4*)gp, *(const f32x4*)(gp + 4));
      short8 g1 = pack8(*(const f32x4*)(gp + 32), *(const f32x4*)(gp + 36));
      f32x4 cX = (f32x4){0.f, 0.f, 0.f, 0.f};
      cX = __builtin_amdgcn_mfma_f32_16x16x32_bf16(aZ[0], g0, cX, 0, 0, 0);
      cX = __builtin_amdgcn_mfma_f32_16x16x32_bf16(aZ[1], g1, cX, 0, 0, 0);
      xr[nt] = cX;
    }

    short8 aC = *(const short8*)&Sz[hl][l16][quad * 8];
    #pragma unroll
    for (int nt = 0; nt < 4; nt++) {
      short8 b = *(const short8*)(vT + (size_t)(h * DH + nt * 16 + l16) * NN + lo + quad * 8);
      xr[nt] = __builtin_amdgcn_mfma_f32_16x16x32_bf16(aC, b, xr[nt], 0, 0, 0);
    }

    #pragma unroll
    for (int nt = 0; nt < 4; nt++)
      #pragma unroll
      for (int g = 0; g < 4; g++)
        __builtin_nontemporal_store(xr[nt][g],
            out + (size_t)(n0 + quad * 4 + g) * (2 * CC) + h * DH + nt * 16 + l16);
  }
}

// ---------------------------------------------------------------------------
extern "C" void kernel_launch(void* const* d_in, const int* in_sizes, int n_in,
                              void* d_out, int out_size, void* d_ws, size_t ws_size,
                              hipStream_t stream) {
  const float* v = (const float*)d_in[1];   // only live input
  float* out = (float*)d_out;

  // ws carve (~27 MB): [Gf 32768] f32, [vnfull][vT] bf16, [Rg] bf16
  float* Gf = (float*)d_ws;
  unsigned short* vnfull = (unsigned short*)(Gf + HEADS * DH * DH);
  unsigned short* vT = vnfull + (size_t)NN * CC;
  unsigned short* Rg = vT + (size_t)NN * CC;

  hipMemsetAsync(Gf, 0, HEADS * DH * DH * sizeof(float), stream);
  k_prep<<<dim3(HEADS * (NN / 64)), dim3(256), 0, stream>>>(v, vnfull, vT, Gf, out);
  k_rgemm<<<dim3(325), dim3(512), 0, stream>>>(vnfull, Rg);   // upper-tri, 8 waves
  k_fused<<<dim3(800 + (NN / 16) * 2), dim3(256), 0, stream>>>(
      Rg, vnfull, Gf, vT, out + (size_t)NN * 2 * CC, out);
}